// Round 3
// baseline (43.164 us; speedup 1.0000x reference)
//
#include <hip/hip_runtime.h>

// Problem: B=4096, N=16, E=512. Outputs: aggregated (B,E) then weights (B,N), f32.
//
// task_anchor @ v_t is a per-b constant across the softmax axis -> dead input
// (softmax shift invariance). Traffic floor: 134.2 MB read + 8.9 MB write.
//
// Structure: 1 wave per b. Pass 1 streams the 16x512 row computing dot(row_n, v_e),
// discarding data (no register tile -> VGPR ~80 -> 4 waves/SIMD instead of 2).
// Pass 2 re-reads the row (guaranteed-warm in L2: re-touched ~2K cycles later,
// L2 turnover ~38K cycles) with nontemporal hint, weighted-accumulates.

#define NB 4096
#define NEXP 16
#define EDIM 512

typedef float f32x4 __attribute__((ext_vector_type(4)));

__global__ __launch_bounds__(256, 4) void meta_attn_kernel(
    const float* __restrict__ expert,   // [B, 16, 512]
    const float* __restrict__ v,        // [640, 1]; v_e = v[0:512]
    float* __restrict__ out_agg,        // [B, 512]
    float* __restrict__ out_w)          // [B, 16]
{
    const int wave = threadIdx.x >> 6;
    const int lane = threadIdx.x & 63;
    const int b = blockIdx.x * 4 + wave;

    const float* row = expert + (size_t)b * (NEXP * EDIM);

    // v reused by every block: regular (cached) loads
    const f32x4 ve0 = *(const f32x4*)(v + 4 * lane);
    const f32x4 ve1 = *(const f32x4*)(v + 256 + 4 * lane);

    float s[NEXP];

    // ---- Pass 1: scores; data discarded after the dot ----
    // Chunks of 4 rows (8 dwordx4 in flight per chunk); compiler pipelines
    // across chunks up to the launch_bounds register cap.
#pragma unroll
    for (int c = 0; c < 4; ++c) {
        f32x4 a[4], d[4];
#pragma unroll
        for (int k = 0; k < 4; ++k) {
            const int n = c * 4 + k;
            a[k] = *(const f32x4*)(row + n * EDIM + 4 * lane);
            d[k] = *(const f32x4*)(row + n * EDIM + 256 + 4 * lane);
        }
#pragma unroll
        for (int k = 0; k < 4; ++k) {
            const int n = c * 4 + k;
            s[n] = a[k].x * ve0.x + a[k].y * ve0.y + a[k].z * ve0.z + a[k].w * ve0.w
                 + d[k].x * ve1.x + d[k].y * ve1.y + d[k].z * ve1.z + d[k].w * ve1.w;
        }
    }

    // Butterfly-reduce each score across the 64-lane wave
#pragma unroll
    for (int n = 0; n < NEXP; ++n) {
        float x = s[n];
#pragma unroll
        for (int m = 1; m < 64; m <<= 1)
            x += __shfl_xor(x, m, 64);
        s[n] = x;
    }

    // Softmax over 16 scores (redundant per lane, no divergence)
    float mx = s[0];
#pragma unroll
    for (int n = 1; n < NEXP; ++n) mx = fmaxf(mx, s[n]);
    float w[NEXP];
    float sum = 0.0f;
#pragma unroll
    for (int n = 0; n < NEXP; ++n) {
        w[n] = __expf(s[n] - mx);
        sum += w[n];
    }
    const float inv = 1.0f / sum;
#pragma unroll
    for (int n = 0; n < NEXP; ++n) w[n] *= inv;

    // Compiler-level memory barrier: forbid CSE of pass-2 loads with pass-1
    // (merging them would re-create the 128-VGPR tile and kill occupancy).
    asm volatile("" ::: "memory");

    // ---- Pass 2: weighted sum; re-read row (L2-warm), nontemporal ----
    f32x4 acc0 = {0.f, 0.f, 0.f, 0.f};
    f32x4 acc1 = {0.f, 0.f, 0.f, 0.f};
#pragma unroll
    for (int c = 0; c < 4; ++c) {
        f32x4 a[4], d[4];
#pragma unroll
        for (int k = 0; k < 4; ++k) {
            const int n = c * 4 + k;
            a[k] = __builtin_nontemporal_load((const f32x4*)(row + n * EDIM + 4 * lane));
            d[k] = __builtin_nontemporal_load((const f32x4*)(row + n * EDIM + 256 + 4 * lane));
        }
#pragma unroll
        for (int k = 0; k < 4; ++k) {
            const int n = c * 4 + k;
            acc0 += w[n] * a[k];
            acc1 += w[n] * d[k];
        }
    }

    __builtin_nontemporal_store(acc0, (f32x4*)(out_agg + (size_t)b * EDIM + 4 * lane));
    __builtin_nontemporal_store(acc1, (f32x4*)(out_agg + (size_t)b * EDIM + 256 + 4 * lane));

    // Weights: per-lane select (compile-time indices) + one coalesced 64B store
    float myw = w[0];
#pragma unroll
    for (int n = 1; n < NEXP; ++n) myw = (lane == n) ? w[n] : myw;
    if (lane < NEXP) out_w[(size_t)b * NEXP + lane] = myw;
}

extern "C" void kernel_launch(void* const* d_in, const int* in_sizes, int n_in,
                              void* d_out, int out_size, void* d_ws, size_t ws_size,
                              hipStream_t stream) {
    // d_in: 0=scene_repr (unused), 1=task_anchor (unused), 2=expert_reprs, 3=v
    const float* expert = (const float*)d_in[2];
    const float* v      = (const float*)d_in[3];
    float* out_agg = (float*)d_out;
    float* out_w   = (float*)d_out + (size_t)NB * EDIM;

    meta_attn_kernel<<<dim3(NB / 4), dim3(256), 0, stream>>>(expert, v, out_agg, out_w);
}

// Round 4
// 26.393 us; speedup vs baseline: 1.6354x; 1.6354x over previous
//
#include <hip/hip_runtime.h>

// Problem: B=4096, N=16, E=512. Outputs: aggregated (B,E) then weights (B,N), f32.
//
// task_anchor @ v_t is a per-b constant across the softmax axis -> dead input
// (softmax shift invariance). Traffic floor: 134.2 MB read + 8.9 MB write.
//
// Structure: one block (4 waves) per b. Wave w owns e-slice [128w,128w+128) of
// all 16 rows -> per-lane register tile = 16 x float2 = 32 VGPRs (vs 128 for
// the whole-row tile) -> 4 waves/SIMD occupancy. Scores: per-slice partial
// dots, multi-value butterfly (17 shuffles, not 96), 256 B LDS cross-wave
// combine. Aggregation reuses the register tile -> expert read exactly once.

#define NB 4096
#define NEXP 16
#define EDIM 512

typedef float f32x2 __attribute__((ext_vector_type(2)));
typedef float f32x4 __attribute__((ext_vector_type(4)));

__global__ __launch_bounds__(256, 4) void meta_attn_kernel(
    const float* __restrict__ expert,   // [B, 16, 512]
    const float* __restrict__ v,        // [640, 1]; v_e = v[0:512]
    float* __restrict__ out_agg,        // [B, 512]
    float* __restrict__ out_w)          // [B, 16]
{
    const int wave = threadIdx.x >> 6;
    const int lane = threadIdx.x & 63;
    const int b = blockIdx.x;

    const int eoff = 128 * wave + 2 * lane;            // this thread's e-offset
    const float* row = expert + (size_t)b * (NEXP * EDIM) + eoff;

    const f32x2 ve = *(const f32x2*)(v + eoff);

    // Register tile: this thread's float2 of every row (32 VGPRs)
    f32x2 tile[NEXP];
#pragma unroll
    for (int n = 0; n < NEXP; ++n)
        tile[n] = *(const f32x2*)(row + n * EDIM);

    // Per-lane partial dots over the 2 owned elements
    float cur[NEXP];
#pragma unroll
    for (int n = 0; n < NEXP; ++n)
        cur[n] = tile[n].x * ve.x + tile[n].y * ve.y;

    // Multi-value butterfly: reduce 16 partials over 64 lanes in 17 shuffles.
    // Each step halves the value count; lane ends owning score rev4(lane&15).
    float t8[8];
    {
        const bool hi = (lane & 1) != 0;
#pragma unroll
        for (int j = 0; j < 8; ++j) {
            const float send = hi ? cur[j] : cur[j + 8];
            const float keep = hi ? cur[j + 8] : cur[j];
            t8[j] = keep + __shfl_xor(send, 1, 64);
        }
    }
    float t4[4];
    {
        const bool hi = (lane & 2) != 0;
#pragma unroll
        for (int j = 0; j < 4; ++j) {
            const float send = hi ? t8[j] : t8[j + 4];
            const float keep = hi ? t8[j + 4] : t8[j];
            t4[j] = keep + __shfl_xor(send, 2, 64);
        }
    }
    float t2[2];
    {
        const bool hi = (lane & 4) != 0;
#pragma unroll
        for (int j = 0; j < 2; ++j) {
            const float send = hi ? t2[j] - t2[j] + t4[j] : t4[j + 2];  // placeholder avoided below
            (void)send;
        }
        // (explicit, no placeholder tricks)
#pragma unroll
        for (int j = 0; j < 2; ++j) {
            const float send2 = hi ? t4[j] : t4[j + 2];
            const float keep2 = hi ? t4[j + 2] : t4[j];
            t2[j] = keep2 + __shfl_xor(send2, 4, 64);
        }
    }
    float t1;
    {
        const bool hi = (lane & 8) != 0;
        const float send = hi ? t2[0] : t2[1];
        const float keep = hi ? t2[1] : t2[0];
        t1 = keep + __shfl_xor(send, 8, 64);
    }
    t1 += __shfl_xor(t1, 16, 64);
    t1 += __shfl_xor(t1, 32, 64);
    // lane (within wave) now holds the wave's partial of score rev4(lane&15)

    // Cross-wave combine via 256 B LDS
    __shared__ float lds_s[NEXP][4];
    if (lane < 16) {
        const int idx = ((lane & 1) << 3) | ((lane & 2) << 1) |
                        ((lane & 4) >> 1) | ((lane & 8) >> 3);
        lds_s[idx][wave] = t1;
    }
    __syncthreads();

    float s[NEXP];
#pragma unroll
    for (int n = 0; n < NEXP; ++n) {
        const f32x4 p = *(const f32x4*)(&lds_s[n][0]);   // broadcast read
        s[n] = (p.x + p.y) + (p.z + p.w);
    }

    // Softmax over 16 scores (redundant per thread, no divergence)
    float mx = s[0];
#pragma unroll
    for (int n = 1; n < NEXP; ++n) mx = fmaxf(mx, s[n]);
    float w[NEXP];
    float sum = 0.0f;
#pragma unroll
    for (int n = 0; n < NEXP; ++n) {
        w[n] = __expf(s[n] - mx);
        sum += w[n];
    }
    const float inv = 1.0f / sum;
#pragma unroll
    for (int n = 0; n < NEXP; ++n) w[n] *= inv;

    // Aggregation from the register tile (no global re-read)
    f32x2 acc = {0.f, 0.f};
#pragma unroll
    for (int n = 0; n < NEXP; ++n) {
        acc.x += w[n] * tile[n].x;
        acc.y += w[n] * tile[n].y;
    }
    *(f32x2*)(out_agg + (size_t)b * EDIM + eoff) = acc;

    // Weights: select chain (compile-time indices) + one coalesced store
    if (wave == 0) {
        float myw = w[0];
#pragma unroll
        for (int n = 1; n < NEXP; ++n) myw = (lane == n) ? w[n] : myw;
        if (lane < NEXP) out_w[(size_t)b * NEXP + lane] = myw;
    }
}

extern "C" void kernel_launch(void* const* d_in, const int* in_sizes, int n_in,
                              void* d_out, int out_size, void* d_ws, size_t ws_size,
                              hipStream_t stream) {
    // d_in: 0=scene_repr (unused), 1=task_anchor (unused), 2=expert_reprs, 3=v
    const float* expert = (const float*)d_in[2];
    const float* v      = (const float*)d_in[3];
    float* out_agg = (float*)d_out;
    float* out_w   = (float*)d_out + (size_t)NB * EDIM;

    meta_attn_kernel<<<dim3(NB), dim3(256), 0, stream>>>(expert, v, out_agg, out_w);
}